// Round 5
// baseline (652.044 us; speedup 1.0000x reference)
//
#include <hip/hip_runtime.h>
#include <math.h>

typedef __attribute__((ext_vector_type(8))) short short8;
typedef __attribute__((ext_vector_type(4))) float float4v;

#define NLAGS 9
#define HID 256
#define GSAMP 16
#define MROWS 144          // GSAMP * NLAGS = 9 M-tiles of 16, exact
#define STR 264            // LDS row stride in bf16 elems
#define F32STR 260         // f32 row stride for final l3 buffer
#define NTHREADS 512
#define SBUF_SHORTS (2 * MROWS * STR)   // 76,032 shorts = 152,064 B (1 block/CU)

union S8 { short8 v; unsigned short u[8]; };

__device__ __forceinline__ float b2f(unsigned short u) {
  union { unsigned int i; float f; } c; c.i = ((unsigned int)u) << 16; return c.f;
}
__device__ __forceinline__ unsigned short f2b(float f) {
  union { float f; unsigned int i; } c; c.f = f;
  return (unsigned short)((c.i + 0x7FFFu + ((c.i >> 16) & 1u)) >> 16);  // RNE
}
__device__ __forceinline__ float sane(float x) {
  return (__builtin_isfinite(x) && fabsf(x) < 1e30f) ? x : 0.0f;
}
__device__ __forceinline__ float ftanh(float x) {
  x = fminf(fmaxf(x, -9.0f), 9.0f);
  float t = __expf(2.0f * x);
  return 1.0f - 2.0f * __builtin_amdgcn_rcpf(t + 1.0f);
}
__device__ __forceinline__ float4v mfma16(short8 a, short8 b, float4v c) {
  return __builtin_amdgcn_mfma_f32_16x16x32_bf16(a, b, c, 0, 0, 0);
}

// ---- prep: f32 weights -> transposed bf16 copies in ws ----
// layout (bf16 elems): Wl2t[256][256] @0, Ww2t @65536, Wm1t[256][512] @131072,
//                      Wm2t[256][512] @262144, Ww1p[256][32] @393216 (K padded 8->32)
__global__ void prep_kernel(const float* __restrict__ Wl2,
                            const float* __restrict__ Ww2,
                            const float* __restrict__ Wm1,
                            const float* __restrict__ Wm2,
                            const float* __restrict__ Ww1,
                            unsigned short* __restrict__ ws)
{
  int idx = blockIdx.x * 256 + threadIdx.x;   // 0..401407
  if (idx < 65536) {
    int n = idx >> 8, k = idx & 255;
    ws[idx] = f2b(sane(Wl2[k * 256 + n]));
  } else if (idx < 131072) {
    int j = idx - 65536; int n = j >> 8, k = j & 255;
    ws[idx] = f2b(sane(Ww2[k * 256 + n]));
  } else if (idx < 262144) {
    int j = idx - 131072; int n = j >> 9, k = j & 511;
    ws[idx] = f2b(sane(Wm1[k * 256 + n]));
  } else if (idx < 393216) {
    int j = idx - 262144; int n = j >> 9, k = j & 511;
    ws[idx] = f2b(sane(Wm2[k * 256 + n]));
  } else if (idx < 401408) {
    int j = idx - 393216; int n = j >> 5, k = j & 31;
    ws[idx] = (k < 8) ? f2b(sane(Ww1[k * 256 + n])) : (unsigned short)0;
  }
}

__global__ void __launch_bounds__(NTHREADS, 2)
fused_kernel(const float* __restrict__ lags,
             const float* __restrict__ weather,
             const float* __restrict__ Wl1,
             const float* __restrict__ bl1,
             const float* __restrict__ gbn,
             const float* __restrict__ bbn,
             const float* __restrict__ bl2,
             const float* __restrict__ bw1,
             const float* __restrict__ bw2,
             const float* __restrict__ bm1,
             const float* __restrict__ bm2,
             const float* __restrict__ Wreg,
             const float* __restrict__ breg,
             const unsigned short* __restrict__ ws,
             float* __restrict__ out)
{
  __shared__ __align__(16) unsigned short sBuf[SBUF_SHORTS];  // 152,064 B
  unsigned short* sL = sBuf;
  unsigned short* sW = sBuf + MROWS * STR;

  const int tid = threadIdx.x;
  const int wave = tid >> 6;
  const int lane16 = tid & 15;
  const int g4 = (tid >> 4) & 3;
  const int s0 = blockIdx.x * GSAMP;

  // 2-D wave tiling: wm in {0,1} -> M-tiles {0..3} / {4..8}; wn in {0..3} -> 64 cols
  const int wm = wave >> 2;
  const int wn = wave & 3;
  const int tbase = wm * 4;
  const int tcnt = 4 + wm;                 // 4 or 5 tiles (wave-uniform)

  const unsigned short* Wl2t = ws;
  const unsigned short* Ww2t = ws + 65536;
  const unsigned short* Wm1t = ws + 131072;
  const unsigned short* Wm2t = ws + 262144;
  const unsigned short* Ww1p = ws + 393216;

  int c[4];                                // wave's four output columns
  #pragma unroll
  for (int j = 0; j < 4; ++j) c[j] = wn * 64 + j * 16 + lane16;

  // ---- Phase A: l0 = BN(tanh(lag * Wl1 + bl1)) -> sL (bf16) ----
  {
    const float BNS = 0.99999500003750f;  // 1/sqrt(1+1e-5)
    #pragma unroll
    for (int i = 0; i < 9; ++i) {
      int cc = tid + i * NTHREADS;      // 4608 chunks of 8 cols, exact
      int row = cc >> 5;                // 0..143
      int h0 = (cc & 31) << 3;          // 0..248
      float lag = sane(lags[s0 * NLAGS + row]);
      float4v w0 = *(const float4v*)(Wl1 + h0);
      float4v w1 = *(const float4v*)(Wl1 + h0 + 4);
      float4v a0 = *(const float4v*)(bl1 + h0);
      float4v a1 = *(const float4v*)(bl1 + h0 + 4);
      float4v g0 = *(const float4v*)(gbn + h0);
      float4v g1 = *(const float4v*)(gbn + h0 + 4);
      float4v q0 = *(const float4v*)(bbn + h0);
      float4v q1 = *(const float4v*)(bbn + h0 + 4);
      S8 o8;
      #pragma unroll
      for (int e = 0; e < 4; ++e) {
        float v = ftanh(fmaf(lag, sane(w0[e]), sane(a0[e])));
        o8.u[e] = f2b(fmaf(v, sane(g0[e]) * BNS, sane(q0[e])));
      }
      #pragma unroll
      for (int e = 0; e < 4; ++e) {
        float v = ftanh(fmaf(lag, sane(w1[e]), sane(a1[e])));
        o8.u[e + 4] = f2b(fmaf(v, sane(g1[e]) * BNS, sane(q1[e])));
      }
      *(short8*)(sL + row * STR + h0) = o8.v;
    }
  }

  // ---- Phase B: w0 = tanh(weather @ Ww1 + bw1); A direct from global (K pad 8->32) ----
  {
    float4v acc[5][4];
    short8 bf[4];
    #pragma unroll
    for (int j = 0; j < 4; ++j)
      bf[j] = *(const short8*)(Ww1p + c[j] * 32 + g4 * 8);
    #pragma unroll
    for (int t = 0; t < 5; ++t) {
      if (t < tcnt) {
        int r = (tbase + t) * 16 + lane16;    // 0..143, exact
        S8 a8;
        if (g4 == 0) {
          float4v x0 = *(const float4v*)(weather + (size_t)(s0 * NLAGS + r) * 8);
          float4v x1 = *(const float4v*)(weather + (size_t)(s0 * NLAGS + r) * 8 + 4);
          #pragma unroll
          for (int e = 0; e < 4; ++e) { a8.u[e] = f2b(sane(x0[e])); a8.u[e+4] = f2b(sane(x1[e])); }
        } else {
          short8 z = {0,0,0,0,0,0,0,0};
          a8.v = z;
        }
        #pragma unroll
        for (int j = 0; j < 4; ++j) {
          float4v zz = {0.f, 0.f, 0.f, 0.f};
          acc[t][j] = mfma16(a8.v, bf[j], zz);
        }
      }
    }
    float bia[4];
    #pragma unroll
    for (int j = 0; j < 4; ++j) bia[j] = sane(bw1[c[j]]);
    #pragma unroll
    for (int t = 0; t < 5; ++t) {
      if (t < tcnt) {
        #pragma unroll
        for (int i = 0; i < 4; ++i) {
          int row = (tbase + t) * 16 + g4 * 4 + i;  // C/D: col=lane&15, row=g4*4+i
          #pragma unroll
          for (int j = 0; j < 4; ++j)
            sW[row * STR + c[j]] = f2b(ftanh(acc[t][j][i] + bia[j]));
        }
      }
    }
  }
  __syncthreads();

  // ---- in-place GEMM (K=256): X = tanh(X @ W + b) ----
  auto gemm256 = [&](unsigned short* Abuf, const unsigned short* Bt,
                     const float* bias) {
    float4v acc[5][4];
    #pragma unroll
    for (int t = 0; t < 5; ++t)
      #pragma unroll
      for (int j = 0; j < 4; ++j) {
        float4v z = {0.f,0.f,0.f,0.f};
        acc[t][j] = z;
      }
    #pragma unroll
    for (int kk = 0; kk < 8; ++kk) {
      short8 b[4];
      #pragma unroll
      for (int j = 0; j < 4; ++j)
        b[j] = *(const short8*)(Bt + c[j] * 256 + kk * 32 + g4 * 8);
      #pragma unroll
      for (int t = 0; t < 5; ++t) {
        if (t < tcnt) {
          short8 a = *(const short8*)(Abuf + ((tbase + t) * 16 + lane16) * STR + kk * 32 + g4 * 8);
          #pragma unroll
          for (int j = 0; j < 4; ++j)
            acc[t][j] = mfma16(a, b[j], acc[t][j]);
        }
      }
    }
    __syncthreads();   // all waves' A reads complete before overwrite
    float bia[4];
    #pragma unroll
    for (int j = 0; j < 4; ++j) bia[j] = sane(bias[c[j]]);
    #pragma unroll
    for (int t = 0; t < 5; ++t) {
      if (t < tcnt) {
        #pragma unroll
        for (int i = 0; i < 4; ++i) {
          int row = (tbase + t) * 16 + g4 * 4 + i;
          #pragma unroll
          for (int j = 0; j < 4; ++j)
            Abuf[row * STR + c[j]] = f2b(ftanh(acc[t][j][i] + bia[j]));
        }
      }
    }
    __syncthreads();
  };

  gemm256(sL, Wl2t, bl2);   // l1
  gemm256(sW, Ww2t, bw2);   // w1

  // ---- per-sample mean aggregation (fixed 9x9 adjacency), in-place, thread-local ----
  // 512 threads = 16 samples x 32 col-chunks of 8
  auto aggregate = [&](unsigned short* buf) {
    int s = tid >> 5;
    int h0 = (tid & 31) << 3;
    float v[9][8];
    #pragma unroll
    for (int r = 0; r < 9; ++r) {
      S8 x; x.v = *(const short8*)(buf + (s * NLAGS + r) * STR + h0);
      #pragma unroll
      for (int e = 0; e < 8; ++e) v[r][e] = b2f(x.u[e]);
    }
    S8 o[9];
    #pragma unroll
    for (int e = 0; e < 8; ++e) {
      o[0].u[e] = f2b(v[8][e]);
      o[1].u[e] = f2b(v[0][e]);
      o[2].u[e] = f2b((1.f/3.f)*v[0][e] + (2.f/3.f)*v[1][e]);
      o[3].u[e] = f2b(0.2f*v[0][e] + 0.4f*v[1][e] + 0.4f*v[2][e]);
      o[4].u[e] = f2b(0.2f*v[1][e] + 0.4f*v[2][e] + 0.4f*v[3][e]);
      o[5].u[e] = f2b(0.2f*v[2][e] + 0.4f*v[3][e] + 0.4f*v[4][e]);
      o[6].u[e] = f2b(0.2f*v[3][e] + 0.4f*v[4][e] + 0.4f*v[5][e]);
      o[7].u[e] = f2b(0.25f*v[4][e] + 0.5f*v[5][e] + 0.25f*v[6][e]);
      o[8].u[e] = f2b((1.f/3.f)*(v[5][e] + v[6][e] + v[7][e]));
    }
    #pragma unroll
    for (int r = 0; r < 9; ++r)
      *(short8*)(buf + (s * NLAGS + r) * STR + h0) = o[r].v;
  };

  aggregate(sL);            // ml1
  aggregate(sW);            // mw1 (becomes w2) -- disjoint buffers, thread-local rows
  __syncthreads();

  // ---- merge GEMM (K=512 over concat(sL,sW)); linear (no tanh) ----
  auto merge = [&](const unsigned short* Bt, const float* bias, bool outf32) {
    float4v acc[5][4];
    #pragma unroll
    for (int t = 0; t < 5; ++t)
      #pragma unroll
      for (int j = 0; j < 4; ++j) {
        float4v z = {0.f,0.f,0.f,0.f};
        acc[t][j] = z;
      }
    #pragma unroll
    for (int kk = 0; kk < 16; ++kk) {
      const unsigned short* Ab = (kk < 8) ? sL : sW;
      int ko = (kk & 7) * 32;
      short8 b[4];
      #pragma unroll
      for (int j = 0; j < 4; ++j)
        b[j] = *(const short8*)(Bt + c[j] * 512 + kk * 32 + g4 * 8);
      #pragma unroll
      for (int t = 0; t < 5; ++t) {
        if (t < tcnt) {
          short8 a = *(const short8*)(Ab + ((tbase + t) * 16 + lane16) * STR + ko + g4 * 8);
          #pragma unroll
          for (int j = 0; j < 4; ++j)
            acc[t][j] = mfma16(a, b[j], acc[t][j]);
        }
      }
    }
    __syncthreads();   // all A reads complete before any overwrite
    float bia[4];
    #pragma unroll
    for (int j = 0; j < 4; ++j) bia[j] = sane(bias[c[j]]);
    if (!outf32) {
      #pragma unroll
      for (int t = 0; t < 5; ++t) {
        if (t < tcnt) {
          #pragma unroll
          for (int i = 0; i < 4; ++i) {
            int row = (tbase + t) * 16 + g4 * 4 + i;
            #pragma unroll
            for (int j = 0; j < 4; ++j)
              sL[row * STR + c[j]] = f2b(acc[t][j][i] + bia[j]);
          }
        }
      }
    } else {
      float* f3 = (float*)sBuf;   // l3 kept f32 for the final dot
      #pragma unroll
      for (int t = 0; t < 5; ++t) {
        if (t < tcnt) {
          #pragma unroll
          for (int i = 0; i < 4; ++i) {
            int row = (tbase + t) * 16 + g4 * 4 + i;
            #pragma unroll
            for (int j = 0; j < 4; ++j)
              f3[row * F32STR + c[j]] = acc[t][j][i] + bia[j];
          }
        }
      }
    }
    __syncthreads();
  };

  merge(Wm1t, bm1, false);  // l2 -> sL ; sW still holds mw1 = w2
  aggregate(sL);            // ml2
  aggregate(sW);            // mw2
  __syncthreads();
  merge(Wm2t, bm2, true);   // l3 -> f32 (143*260+256 = 37,436 f32 = 149,744 B, fits)

  // ---- final regression: out[b] = sum_{d,h} l3[b,d,h] * Wreg[d*256+h] + breg ----
  {
    int s = tid >> 5;
    int t32 = tid & 31;
    int h0 = t32 << 3;
    const float* f3 = (const float*)sBuf;
    float sum = 0.f;
    #pragma unroll
    for (int d = 0; d < 9; ++d) {
      const float* rp = f3 + (s * NLAGS + d) * F32STR + h0;
      float4v x0 = *(const float4v*)(rp);
      float4v x1 = *(const float4v*)(rp + 4);
      float4v r0 = *(const float4v*)(Wreg + d * 256 + h0);
      float4v r1 = *(const float4v*)(Wreg + d * 256 + h0 + 4);
      #pragma unroll
      for (int e = 0; e < 4; ++e) sum = fmaf(x0[e], sane(r0[e]), sum);
      #pragma unroll
      for (int e = 0; e < 4; ++e) sum = fmaf(x1[e], sane(r1[e]), sum);
    }
    sum += __shfl_down(sum, 16, 32);
    sum += __shfl_down(sum, 8, 32);
    sum += __shfl_down(sum, 4, 32);
    sum += __shfl_down(sum, 2, 32);
    sum += __shfl_down(sum, 1, 32);
    if (t32 == 0) out[s0 + s] = sum + sane(breg[0]);
  }
}

extern "C" void kernel_launch(void* const* d_in, const int* in_sizes, int n_in,
                              void* d_out, int out_size, void* d_ws, size_t ws_size,
                              hipStream_t stream) {
  const float* lags    = (const float*)d_in[0];
  const float* weather = (const float*)d_in[1];
  const float* Wl1     = (const float*)d_in[2];
  const float* bl1     = (const float*)d_in[3];
  const float* gbn     = (const float*)d_in[4];
  const float* bbn     = (const float*)d_in[5];
  const float* Wl2     = (const float*)d_in[6];
  const float* bl2     = (const float*)d_in[7];
  const float* Ww1     = (const float*)d_in[8];
  const float* bw1     = (const float*)d_in[9];
  const float* Ww2     = (const float*)d_in[10];
  const float* bw2     = (const float*)d_in[11];
  const float* Wm1     = (const float*)d_in[12];
  const float* bm1     = (const float*)d_in[13];
  const float* Wm2     = (const float*)d_in[14];
  const float* bm2     = (const float*)d_in[15];
  const float* Wreg    = (const float*)d_in[16];
  const float* breg    = (const float*)d_in[17];
  unsigned short* ws = (unsigned short*)d_ws;

  prep_kernel<<<1568, 256, 0, stream>>>(Wl2, Ww2, Wm1, Wm2, Ww1, ws);

  const int nblocks = 32768 / GSAMP;  // 2048
  fused_kernel<<<nblocks, NTHREADS, 0, stream>>>(
      lags, weather, Wl1, bl1, gbn, bbn, bl2, bw1, bw2, bm1, bm2,
      Wreg, breg, ws, (float*)d_out);
}

// Round 6
// 598.704 us; speedup vs baseline: 1.0891x; 1.0891x over previous
//
#include <hip/hip_runtime.h>
#include <math.h>

typedef __attribute__((ext_vector_type(8))) short short8;
typedef __attribute__((ext_vector_type(4))) float float4v;

#define NLAGS 9
#define HID 256
#define GSAMP 16
#define MROWS 144          // GSAMP * NLAGS = 9 M-tiles of 16, exact
#define STR 264            // LDS row stride in bf16 elems
#define F32STR 260         // f32 row stride for final l3 buffer
#define NTHREADS 512
#define SBUF_SHORTS (2 * MROWS * STR)   // 76,032 shorts = 152,064 B (1 block/CU)

union S8 { short8 v; unsigned short u[8]; };

__device__ __forceinline__ float b2f(unsigned short u) {
  union { unsigned int i; float f; } c; c.i = ((unsigned int)u) << 16; return c.f;
}
__device__ __forceinline__ unsigned short f2b(float f) {
  union { float f; unsigned int i; } c; c.f = f;
  return (unsigned short)((c.i + 0x7FFFu + ((c.i >> 16) & 1u)) >> 16);  // RNE
}
__device__ __forceinline__ float sane(float x) {
  return (__builtin_isfinite(x) && fabsf(x) < 1e30f) ? x : 0.0f;
}
// unclamped: exp(2x)->0 gives -1, ->inf gives rcp(inf)=0 -> +1; finite-in => finite-out
__device__ __forceinline__ float ftanh(float x) {
  float t = __expf(2.0f * x);
  return 1.0f - 2.0f * __builtin_amdgcn_rcpf(t + 1.0f);
}
__device__ __forceinline__ float4v mfma16(short8 a, short8 b, float4v c) {
  return __builtin_amdgcn_mfma_f32_16x16x32_bf16(a, b, c, 0, 0, 0);
}

// ---- prep: f32 weights -> transposed bf16 copies in ws (sanitized here, free) ----
// layout (bf16 elems): Wl2t[256][256] @0, Ww2t @65536, Wm1t[256][512] @131072,
//                      Wm2t[256][512] @262144, Ww1p[256][32] @393216 (K padded 8->32)
__global__ void prep_kernel(const float* __restrict__ Wl2,
                            const float* __restrict__ Ww2,
                            const float* __restrict__ Wm1,
                            const float* __restrict__ Wm2,
                            const float* __restrict__ Ww1,
                            unsigned short* __restrict__ ws)
{
  int idx = blockIdx.x * 256 + threadIdx.x;   // 0..401407
  if (idx < 65536) {
    int n = idx >> 8, k = idx & 255;
    ws[idx] = f2b(sane(Wl2[k * 256 + n]));
  } else if (idx < 131072) {
    int j = idx - 65536; int n = j >> 8, k = j & 255;
    ws[idx] = f2b(sane(Ww2[k * 256 + n]));
  } else if (idx < 262144) {
    int j = idx - 131072; int n = j >> 9, k = j & 511;
    ws[idx] = f2b(sane(Wm1[k * 256 + n]));
  } else if (idx < 393216) {
    int j = idx - 262144; int n = j >> 9, k = j & 511;
    ws[idx] = f2b(sane(Wm2[k * 256 + n]));
  } else if (idx < 401408) {
    int j = idx - 393216; int n = j >> 5, k = j & 31;
    ws[idx] = (k < 8) ? f2b(sane(Ww1[k * 256 + n])) : (unsigned short)0;
  }
}

__global__ void __launch_bounds__(NTHREADS, 2)
fused_kernel(const float* __restrict__ lags,
             const float* __restrict__ weather,
             const float* __restrict__ Wl1,
             const float* __restrict__ bl1,
             const float* __restrict__ gbn,
             const float* __restrict__ bbn,
             const float* __restrict__ bl2,
             const float* __restrict__ bw1,
             const float* __restrict__ bw2,
             const float* __restrict__ bm1,
             const float* __restrict__ bm2,
             const float* __restrict__ Wreg,
             const float* __restrict__ breg,
             const unsigned short* __restrict__ ws,
             float* __restrict__ out)
{
  __shared__ __align__(16) unsigned short sBuf[SBUF_SHORTS];  // 152,064 B
  unsigned short* sL = sBuf;
  unsigned short* sW = sBuf + MROWS * STR;

  const int tid = threadIdx.x;
  const int wave = tid >> 6;
  const int lane16 = tid & 15;
  const int g4 = (tid >> 4) & 3;
  const int s0 = blockIdx.x * GSAMP;

  const unsigned short* Wl2t = ws;
  const unsigned short* Ww2t = ws + 65536;
  const unsigned short* Wm1t = ws + 131072;
  const unsigned short* Wm2t = ws + 262144;
  const unsigned short* Ww1p = ws + 393216;

  const int c0 = wave * 32 + lane16;       // wave's two output columns (1x B coverage)
  const int c1 = wave * 32 + 16 + lane16;

  // ---- Phase A: l0 = BN(tanh(lag * Wl1 + bl1)) -> sL (bf16) ----
  // h0 is loop-invariant per thread: weight loads hoisted; gbn*BNS pre-folded.
  {
    const float BNS = 0.99999500003750f;  // 1/sqrt(1+1e-5)
    const int rb = tid >> 5;              // 0..15
    const int h0 = (tid & 31) << 3;       // 0..248, fixed per thread
    float4v w0 = *(const float4v*)(Wl1 + h0);
    float4v w1 = *(const float4v*)(Wl1 + h0 + 4);
    float4v a0 = *(const float4v*)(bl1 + h0);
    float4v a1 = *(const float4v*)(bl1 + h0 + 4);
    float4v g0 = *(const float4v*)(gbn + h0);
    float4v g1 = *(const float4v*)(gbn + h0 + 4);
    float4v q0 = *(const float4v*)(bbn + h0);
    float4v q1 = *(const float4v*)(bbn + h0 + 4);
    #pragma unroll
    for (int e = 0; e < 4; ++e) { g0[e] *= BNS; g1[e] *= BNS; }
    #pragma unroll
    for (int i = 0; i < 9; ++i) {
      int row = rb + i * 16;              // 0..143, exact coverage
      float lag = lags[s0 * NLAGS + row];
      S8 o8;
      #pragma unroll
      for (int e = 0; e < 4; ++e) {
        float v = ftanh(fmaf(lag, w0[e], a0[e]));
        o8.u[e] = f2b(fmaf(v, g0[e], q0[e]));
      }
      #pragma unroll
      for (int e = 0; e < 4; ++e) {
        float v = ftanh(fmaf(lag, w1[e], a1[e]));
        o8.u[e + 4] = f2b(fmaf(v, g1[e], q1[e]));
      }
      *(short8*)(sL + row * STR + h0) = o8.v;
    }
  }

  // ---- Phase B: w0 = tanh(weather @ Ww1 + bw1); A direct from global (K pad 8->32) ----
  {
    float4v acc0[9], acc1[9];
    short8 bf0 = *(const short8*)(Ww1p + c0 * 32 + g4 * 8);
    short8 bf1 = *(const short8*)(Ww1p + c1 * 32 + g4 * 8);
    #pragma unroll
    for (int m = 0; m < 9; ++m) {
      int r = m * 16 + lane16;            // 0..143, exact
      S8 a8;
      if (g4 == 0) {
        float4v x0 = *(const float4v*)(weather + (size_t)(s0 * NLAGS + r) * 8);
        float4v x1 = *(const float4v*)(weather + (size_t)(s0 * NLAGS + r) * 8 + 4);
        #pragma unroll
        for (int e = 0; e < 4; ++e) { a8.u[e] = f2b(x0[e]); a8.u[e+4] = f2b(x1[e]); }
      } else {
        short8 z = {0,0,0,0,0,0,0,0};
        a8.v = z;
      }
      float4v zz = {0.f, 0.f, 0.f, 0.f};
      acc0[m] = mfma16(a8.v, bf0, zz);
      acc1[m] = mfma16(a8.v, bf1, zz);
    }
    float bia0 = bw1[c0], bia1 = bw1[c1];
    #pragma unroll
    for (int m = 0; m < 9; ++m) {
      #pragma unroll
      for (int i = 0; i < 4; ++i) {
        int row = m * 16 + g4 * 4 + i;    // C/D: col=lane&15, row=(lane>>4)*4+i
        sW[row * STR + c0] = f2b(ftanh(acc0[m][i] + bia0));
        sW[row * STR + c1] = f2b(ftanh(acc1[m][i] + bia1));
      }
    }
  }
  __syncthreads();

  // ---- DUAL in-place GEMM (K=256): sL = tanh(sL@Wl2+bl2), sW = tanh(sW@Ww2+bw2) ----
  // 36 independent MFMA chains per wave -> hides MFMA + L2-B-load latency.
  {
    float4v aL0[9], aL1[9], aW0[9], aW1[9];   // 144 VGPR acc
    #pragma unroll
    for (int m = 0; m < 9; ++m) {
      float4v z = {0.f,0.f,0.f,0.f};
      aL0[m] = z; aL1[m] = z; aW0[m] = z; aW1[m] = z;
    }
    #pragma unroll
    for (int kk = 0; kk < 8; ++kk) {
      short8 bL0 = *(const short8*)(Wl2t + c0 * 256 + kk * 32 + g4 * 8);
      short8 bL1 = *(const short8*)(Wl2t + c1 * 256 + kk * 32 + g4 * 8);
      short8 bW0 = *(const short8*)(Ww2t + c0 * 256 + kk * 32 + g4 * 8);
      short8 bW1 = *(const short8*)(Ww2t + c1 * 256 + kk * 32 + g4 * 8);
      #pragma unroll
      for (int m = 0; m < 9; ++m) {
        int ao = (m * 16 + lane16) * STR + kk * 32 + g4 * 8;
        short8 aL = *(const short8*)(sL + ao);
        short8 aW = *(const short8*)(sW + ao);
        aL0[m] = mfma16(aL, bL0, aL0[m]);
        aL1[m] = mfma16(aL, bL1, aL1[m]);
        aW0[m] = mfma16(aW, bW0, aW0[m]);
        aW1[m] = mfma16(aW, bW1, aW1[m]);
      }
    }
    __syncthreads();   // all waves' A reads complete before overwrite
    float bL0b = bl2[c0], bL1b = bl2[c1];
    float bW0b = bw2[c0], bW1b = bw2[c1];
    #pragma unroll
    for (int m = 0; m < 9; ++m) {
      #pragma unroll
      for (int i = 0; i < 4; ++i) {
        int row = m * 16 + g4 * 4 + i;
        sL[row * STR + c0] = f2b(ftanh(aL0[m][i] + bL0b));
        sL[row * STR + c1] = f2b(ftanh(aL1[m][i] + bL1b));
        sW[row * STR + c0] = f2b(ftanh(aW0[m][i] + bW0b));
        sW[row * STR + c1] = f2b(ftanh(aW1[m][i] + bW1b));
      }
    }
    __syncthreads();
  }

  // ---- per-sample mean aggregation (fixed 9x9 adjacency), in-place, thread-local ----
  auto aggregate = [&](unsigned short* buf) {
    int s = tid >> 5;
    int h0 = (tid & 31) << 3;
    float v[9][8];
    #pragma unroll
    for (int r = 0; r < 9; ++r) {
      S8 x; x.v = *(const short8*)(buf + (s * NLAGS + r) * STR + h0);
      #pragma unroll
      for (int e = 0; e < 8; ++e) v[r][e] = b2f(x.u[e]);
    }
    S8 o[9];
    #pragma unroll
    for (int e = 0; e < 8; ++e) {
      o[0].u[e] = f2b(v[8][e]);
      o[1].u[e] = f2b(v[0][e]);
      o[2].u[e] = f2b((1.f/3.f)*v[0][e] + (2.f/3.f)*v[1][e]);
      o[3].u[e] = f2b(0.2f*v[0][e] + 0.4f*v[1][e] + 0.4f*v[2][e]);
      o[4].u[e] = f2b(0.2f*v[1][e] + 0.4f*v[2][e] + 0.4f*v[3][e]);
      o[5].u[e] = f2b(0.2f*v[2][e] + 0.4f*v[3][e] + 0.4f*v[4][e]);
      o[6].u[e] = f2b(0.2f*v[3][e] + 0.4f*v[4][e] + 0.4f*v[5][e]);
      o[7].u[e] = f2b(0.25f*v[4][e] + 0.5f*v[5][e] + 0.25f*v[6][e]);
      o[8].u[e] = f2b((1.f/3.f)*(v[5][e] + v[6][e] + v[7][e]));
    }
    #pragma unroll
    for (int r = 0; r < 9; ++r)
      *(short8*)(buf + (s * NLAGS + r) * STR + h0) = o[r].v;
  };

  aggregate(sL);            // ml1
  aggregate(sW);            // mw1 (becomes w2) -- disjoint, thread-local
  __syncthreads();

  // ---- merge GEMM (K=512 over concat(sL,sW)); linear (no tanh) ----
  auto merge = [&](const unsigned short* Bt, const float* bias, bool outf32) {
    float4v acc0[9], acc1[9];
    #pragma unroll
    for (int m = 0; m < 9; ++m) {
      float4v z = {0.f,0.f,0.f,0.f};
      acc0[m] = z; acc1[m] = z;
    }
    #pragma unroll
    for (int kk = 0; kk < 16; ++kk) {
      const unsigned short* Ab = (kk < 8) ? sL : sW;
      int ko = (kk & 7) * 32;
      short8 b0 = *(const short8*)(Bt + c0 * 512 + kk * 32 + g4 * 8);
      short8 b1 = *(const short8*)(Bt + c1 * 512 + kk * 32 + g4 * 8);
      #pragma unroll
      for (int m = 0; m < 9; ++m) {
        short8 a = *(const short8*)(Ab + (m * 16 + lane16) * STR + ko + g4 * 8);
        acc0[m] = mfma16(a, b0, acc0[m]);
        acc1[m] = mfma16(a, b1, acc1[m]);
      }
    }
    __syncthreads();   // all A reads complete before any overwrite
    float bia0 = bias[c0], bia1 = bias[c1];
    if (!outf32) {
      #pragma unroll
      for (int m = 0; m < 9; ++m) {
        #pragma unroll
        for (int i = 0; i < 4; ++i) {
          int row = m * 16 + g4 * 4 + i;
          sL[row * STR + c0] = f2b(acc0[m][i] + bia0);
          sL[row * STR + c1] = f2b(acc1[m][i] + bia1);
        }
      }
    } else {
      float* f3 = (float*)sBuf;   // l3 kept f32 for the final dot
      #pragma unroll
      for (int m = 0; m < 9; ++m) {
        #pragma unroll
        for (int i = 0; i < 4; ++i) {
          int row = m * 16 + g4 * 4 + i;
          f3[row * F32STR + c0] = acc0[m][i] + bia0;
          f3[row * F32STR + c1] = acc1[m][i] + bia1;
        }
      }
    }
    __syncthreads();
  };

  merge(Wm1t, bm1, false);  // l2 -> sL ; sW still holds mw1 = w2
  aggregate(sL);            // ml2
  aggregate(sW);            // mw2
  __syncthreads();
  merge(Wm2t, bm2, true);   // l3 -> f32 (143*260+256 = 37,436 f32 = 149,744 B, fits)

  // ---- final regression: out[b] = sum_{d,h} l3[b,d,h] * Wreg[d*256+h] + breg ----
  {
    int s = tid >> 5;
    int t32 = tid & 31;
    int h0 = t32 << 3;
    const float* f3 = (const float*)sBuf;
    float sum = 0.f;
    #pragma unroll
    for (int d = 0; d < 9; ++d) {
      const float* rp = f3 + (s * NLAGS + d) * F32STR + h0;
      float4v x0 = *(const float4v*)(rp);
      float4v x1 = *(const float4v*)(rp + 4);
      float4v r0 = *(const float4v*)(Wreg + d * 256 + h0);
      float4v r1 = *(const float4v*)(Wreg + d * 256 + h0 + 4);
      #pragma unroll
      for (int e = 0; e < 4; ++e) sum = fmaf(x0[e], r0[e], sum);
      #pragma unroll
      for (int e = 0; e < 4; ++e) sum = fmaf(x1[e], r1[e], sum);
    }
    sum += __shfl_down(sum, 16, 32);
    sum += __shfl_down(sum, 8, 32);
    sum += __shfl_down(sum, 4, 32);
    sum += __shfl_down(sum, 2, 32);
    sum += __shfl_down(sum, 1, 32);
    if (t32 == 0) out[s0 + s] = sum + breg[0];
  }
}

extern "C" void kernel_launch(void* const* d_in, const int* in_sizes, int n_in,
                              void* d_out, int out_size, void* d_ws, size_t ws_size,
                              hipStream_t stream) {
  const float* lags    = (const float*)d_in[0];
  const float* weather = (const float*)d_in[1];
  const float* Wl1     = (const float*)d_in[2];
  const float* bl1     = (const float*)d_in[3];
  const float* gbn     = (const float*)d_in[4];
  const float* bbn     = (const float*)d_in[5];
  const float* Wl2     = (const float*)d_in[6];
  const float* bl2     = (const float*)d_in[7];
  const float* Ww1     = (const float*)d_in[8];
  const float* bw1     = (const float*)d_in[9];
  const float* Ww2     = (const float*)d_in[10];
  const float* bw2     = (const float*)d_in[11];
  const float* Wm1     = (const float*)d_in[12];
  const float* bm1     = (const float*)d_in[13];
  const float* Wm2     = (const float*)d_in[14];
  const float* bm2     = (const float*)d_in[15];
  const float* Wreg    = (const float*)d_in[16];
  const float* breg    = (const float*)d_in[17];
  unsigned short* ws = (unsigned short*)d_ws;

  prep_kernel<<<1568, 256, 0, stream>>>(Wl2, Ww2, Wm1, Wm2, Ww1, ws);

  const int nblocks = 32768 / GSAMP;  // 2048
  fused_kernel<<<nblocks, NTHREADS, 0, stream>>>(
      lags, weather, Wl1, bl1, gbn, bbn, bl2, bw1, bw2, bm1, bm2,
      Wreg, breg, ws, (float*)d_out);
}

// Round 7
// 419.023 us; speedup vs baseline: 1.5561x; 1.4288x over previous
//
#include <hip/hip_runtime.h>

typedef __attribute__((ext_vector_type(8))) short short8;
typedef __attribute__((ext_vector_type(4))) float float4v;

#define NLAGS 9
#define HID 256
#define GSAMP 16
#define MROWS 144          // 9 lag-tiles of 16 samples (LAG-MAJOR: row = lag*16 + sample)
#define STR 264            // LDS row stride in bf16 elems
#define F32STR 260         // f32 row stride for final l3 buffer
#define NTHREADS 512
#define SBUF_SHORTS (2 * MROWS * STR)   // 152,064 B (1 block/CU)

union S8 { short8 v; unsigned short u[8]; };

__device__ __forceinline__ float b2f(unsigned short u) {
  union { unsigned int i; float f; } c; c.i = ((unsigned int)u) << 16; return c.f;
}
__device__ __forceinline__ unsigned short f2b(float f) {
  union { float f; unsigned int i; } c; c.f = f;
  return (unsigned short)((c.i + 0x7FFFu + ((c.i >> 16) & 1u)) >> 16);  // RNE
}
__device__ __forceinline__ float sane(float x) {
  return (__builtin_isfinite(x) && fabsf(x) < 1e30f) ? x : 0.0f;
}
// HW packed f32->bf16 (RNE), 1 VALU op for 2 conversions
__device__ __forceinline__ unsigned int pkbf16(float lo, float hi) {
  unsigned int r;
  asm("v_cvt_pk_bf16_f32 %0, %1, %2" : "=v"(r) : "v"(lo), "v"(hi));
  return r;
}
// unclamped tanh: exp->0 gives -1, exp->inf gives +1; finite-in => finite-out
__device__ __forceinline__ float ftanh(float x) {
  float t = __expf(2.0f * x);
  return 1.0f - 2.0f * __builtin_amdgcn_rcpf(t + 1.0f);
}
__device__ __forceinline__ float4v mfma16(short8 a, short8 b, float4v c) {
  return __builtin_amdgcn_mfma_f32_16x16x32_bf16(a, b, c, 0, 0, 0);
}

// ---- prep: f32 weights -> transposed bf16 copies in ws (sanitized once here) ----
// layout (bf16 elems): Wl2t[256][256] @0, Ww2t @65536, Wm1t[256][512] @131072,
//                      Wm2t[256][512] @262144, Ww1p[256][32] @393216 (K padded 8->32)
__global__ void prep_kernel(const float* __restrict__ Wl2,
                            const float* __restrict__ Ww2,
                            const float* __restrict__ Wm1,
                            const float* __restrict__ Wm2,
                            const float* __restrict__ Ww1,
                            unsigned short* __restrict__ ws)
{
  int idx = blockIdx.x * 256 + threadIdx.x;   // 0..401407
  if (idx < 65536) {
    int n = idx >> 8, k = idx & 255;
    ws[idx] = f2b(sane(Wl2[k * 256 + n]));
  } else if (idx < 131072) {
    int j = idx - 65536; int n = j >> 8, k = j & 255;
    ws[idx] = f2b(sane(Ww2[k * 256 + n]));
  } else if (idx < 262144) {
    int j = idx - 131072; int n = j >> 9, k = j & 511;
    ws[idx] = f2b(sane(Wm1[k * 256 + n]));
  } else if (idx < 393216) {
    int j = idx - 262144; int n = j >> 9, k = j & 511;
    ws[idx] = f2b(sane(Wm2[k * 256 + n]));
  } else if (idx < 401408) {
    int j = idx - 393216; int n = j >> 5, k = j & 31;
    ws[idx] = (k < 8) ? f2b(sane(Ww1[k * 256 + n])) : (unsigned short)0;
  }
}

__global__ void __launch_bounds__(NTHREADS, 2)
fused_kernel(const float* __restrict__ lags,
             const float* __restrict__ weather,
             const float* __restrict__ Wl1,
             const float* __restrict__ bl1,
             const float* __restrict__ gbn,
             const float* __restrict__ bbn,
             const float* __restrict__ bl2,
             const float* __restrict__ bw1,
             const float* __restrict__ bw2,
             const float* __restrict__ bm1,
             const float* __restrict__ bm2,
             const float* __restrict__ Wreg,
             const float* __restrict__ breg,
             const unsigned short* __restrict__ ws,
             float* __restrict__ out)
{
  __shared__ __align__(16) unsigned short sBuf[SBUF_SHORTS];  // 152,064 B
  unsigned short* sL = sBuf;
  unsigned short* sW = sBuf + MROWS * STR;

  const int tid = threadIdx.x;
  const int wave = tid >> 6;
  const int lane16 = tid & 15;
  const int g4 = (tid >> 4) & 3;
  const int s0 = blockIdx.x * GSAMP;

  const unsigned short* Wl2t = ws;
  const unsigned short* Ww2t = ws + 65536;
  const unsigned short* Wm1t = ws + 131072;
  const unsigned short* Wm2t = ws + 262144;
  const unsigned short* Ww1p = ws + 393216;

  const int c0 = wave * 32 + lane16;       // wave's two output columns
  const int c1 = wave * 32 + 16 + lane16;

  // in-register lag-axis aggregation: acc[m] indexed by lag tile m
  auto applyA = [&](float4v (&a)[9]) {
    #pragma unroll
    for (int i = 0; i < 4; ++i) {
      float v0=a[0][i],v1=a[1][i],v2=a[2][i],v3=a[3][i],v4=a[4][i];
      float v5=a[5][i],v6=a[6][i],v7=a[7][i],v8=a[8][i];
      a[0][i]=v8;
      a[1][i]=v0;
      a[2][i]=(1.f/3.f)*v0+(2.f/3.f)*v1;
      a[3][i]=0.2f*v0+0.4f*v1+0.4f*v2;
      a[4][i]=0.2f*v1+0.4f*v2+0.4f*v3;
      a[5][i]=0.2f*v2+0.4f*v3+0.4f*v4;
      a[6][i]=0.2f*v3+0.4f*v4+0.4f*v5;
      a[7][i]=0.25f*v4+0.5f*v5+0.25f*v6;
      a[8][i]=(1.f/3.f)*(v5+v6+v7);
    }
  };

  // ---- Phase A: l0 = BN(tanh(lag*Wl1+bl1)) -> sL, lag-major rows ----
  {
    const float BNS = 0.99999500003750f;  // 1/sqrt(1+1e-5)
    const int samp = tid >> 5;            // 0..15
    const int h0 = (tid & 31) << 3;       // fixed col chunk per thread
    float4v w0 = *(const float4v*)(Wl1 + h0);
    float4v w1 = *(const float4v*)(Wl1 + h0 + 4);
    float4v a0 = *(const float4v*)(bl1 + h0);
    float4v a1 = *(const float4v*)(bl1 + h0 + 4);
    float4v g0 = *(const float4v*)(gbn + h0);
    float4v g1 = *(const float4v*)(gbn + h0 + 4);
    float4v q0 = *(const float4v*)(bbn + h0);
    float4v q1 = *(const float4v*)(bbn + h0 + 4);
    #pragma unroll
    for (int e = 0; e < 4; ++e) { g0[e] *= BNS; g1[e] *= BNS; }
    #pragma unroll
    for (int d = 0; d < 9; ++d) {         // d = lag
      int row = d * 16 + samp;
      float lag = lags[(s0 + samp) * NLAGS + d];
      float t[8];
      #pragma unroll
      for (int e = 0; e < 4; ++e) {
        float v = ftanh(fmaf(lag, w0[e], a0[e]));
        t[e] = fmaf(v, g0[e], q0[e]);
        float v2 = ftanh(fmaf(lag, w1[e], a1[e]));
        t[e + 4] = fmaf(v2, g1[e], q1[e]);
      }
      uint4 o;
      o.x = pkbf16(t[0], t[1]); o.y = pkbf16(t[2], t[3]);
      o.z = pkbf16(t[4], t[5]); o.w = pkbf16(t[6], t[7]);
      *(uint4*)(sL + row * STR + h0) = o;
    }
  }

  // ---- Phase B: w0 = tanh(weather @ Ww1 + bw1) -> sW (K pad 8->32) ----
  {
    float4v acc0[9], acc1[9];
    short8 bf0 = *(const short8*)(Ww1p + c0 * 32 + g4 * 8);
    short8 bf1 = *(const short8*)(Ww1p + c1 * 32 + g4 * 8);
    #pragma unroll
    for (int m = 0; m < 9; ++m) {         // m = lag tile; row-in-tile = sample = lane16
      S8 a8;
      if (g4 == 0) {
        const float* wp = weather + (size_t)(s0 + lane16) * 72 + m * 8;
        float4v x0 = *(const float4v*)(wp);
        float4v x1 = *(const float4v*)(wp + 4);
        a8.v = (short8){0,0,0,0,0,0,0,0};
        unsigned int p0 = pkbf16(x0[0], x0[1]), p1 = pkbf16(x0[2], x0[3]);
        unsigned int p2 = pkbf16(x1[0], x1[1]), p3 = pkbf16(x1[2], x1[3]);
        a8.u[0] = (unsigned short)p0; a8.u[1] = (unsigned short)(p0 >> 16);
        a8.u[2] = (unsigned short)p1; a8.u[3] = (unsigned short)(p1 >> 16);
        a8.u[4] = (unsigned short)p2; a8.u[5] = (unsigned short)(p2 >> 16);
        a8.u[6] = (unsigned short)p3; a8.u[7] = (unsigned short)(p3 >> 16);
      } else {
        a8.v = (short8){0,0,0,0,0,0,0,0};
      }
      float4v zz = {0.f, 0.f, 0.f, 0.f};
      acc0[m] = mfma16(a8.v, bf0, zz);
      acc1[m] = mfma16(a8.v, bf1, zz);
    }
    float bia0 = bw1[c0], bia1 = bw1[c1];
    #pragma unroll
    for (int m = 0; m < 9; ++m) {
      #pragma unroll
      for (int i = 0; i < 4; ++i) {
        int row = m * 16 + g4 * 4 + i;    // C/D: col=lane&15, row=(lane>>4)*4+i
        unsigned int p = pkbf16(ftanh(acc0[m][i] + bia0), ftanh(acc1[m][i] + bia1));
        sW[row * STR + c0] = (unsigned short)p;
        sW[row * STR + c1] = (unsigned short)(p >> 16);
      }
    }
  }
  __syncthreads();

  // ---- in-place GEMM (K=256): X = tanh(X @ W + b) ----
  auto gemm256 = [&](unsigned short* Abuf, const unsigned short* Bt, const float* bias) {
    float4v acc0[9], acc1[9];
    #pragma unroll
    for (int m = 0; m < 9; ++m) {
      float4v z = {0.f,0.f,0.f,0.f};
      acc0[m] = z; acc1[m] = z;
    }
    #pragma unroll
    for (int kk = 0; kk < 8; ++kk) {
      short8 b0 = *(const short8*)(Bt + c0 * 256 + kk * 32 + g4 * 8);
      short8 b1 = *(const short8*)(Bt + c1 * 256 + kk * 32 + g4 * 8);
      #pragma unroll
      for (int m = 0; m < 9; ++m) {
        short8 a = *(const short8*)(Abuf + (m * 16 + lane16) * STR + kk * 32 + g4 * 8);
        acc0[m] = mfma16(a, b0, acc0[m]);
        acc1[m] = mfma16(a, b1, acc1[m]);
      }
    }
    __syncthreads();   // all waves' A reads complete before in-place overwrite
    float bia0 = bias[c0], bia1 = bias[c1];
    #pragma unroll
    for (int m = 0; m < 9; ++m) {
      #pragma unroll
      for (int i = 0; i < 4; ++i) {
        int row = m * 16 + g4 * 4 + i;
        unsigned int p = pkbf16(ftanh(acc0[m][i] + bia0), ftanh(acc1[m][i] + bia1));
        Abuf[row * STR + c0] = (unsigned short)p;
        Abuf[row * STR + c1] = (unsigned short)(p >> 16);
      }
    }
    __syncthreads();
  };

  gemm256(sL, Wl2t, bl2);   // l1 (lag-major)
  gemm256(sW, Ww2t, bw2);   // w1 -- sW is FINAL after this; never rewritten

  // ---- merge1: l2 = A·(l1@Wm1top + w1@Wm1bot) + bm1  -> sL ----
  {
    float4v acc0[9], acc1[9];
    #pragma unroll
    for (int m = 0; m < 9; ++m) {
      float4v z = {0.f,0.f,0.f,0.f};
      acc0[m] = z; acc1[m] = z;
    }
    #pragma unroll
    for (int kk = 0; kk < 16; ++kk) {
      const unsigned short* Ab = (kk < 8) ? sL : sW;
      int ko = (kk & 7) * 32;
      short8 b0 = *(const short8*)(Wm1t + c0 * 512 + kk * 32 + g4 * 8);
      short8 b1 = *(const short8*)(Wm1t + c1 * 512 + kk * 32 + g4 * 8);
      #pragma unroll
      for (int m = 0; m < 9; ++m) {
        short8 a = *(const short8*)(Ab + (m * 16 + lane16) * STR + ko + g4 * 8);
        acc0[m] = mfma16(a, b0, acc0[m]);
        acc1[m] = mfma16(a, b1, acc1[m]);
      }
    }
    __syncthreads();   // all sL reads complete before overwrite
    applyA(acc0); applyA(acc1);
    float bia0 = bm1[c0], bia1 = bm1[c1];
    #pragma unroll
    for (int m = 0; m < 9; ++m) {
      #pragma unroll
      for (int i = 0; i < 4; ++i) {
        int row = m * 16 + g4 * 4 + i;
        unsigned int p = pkbf16(acc0[m][i] + bia0, acc1[m][i] + bia1);
        sL[row * STR + c0] = (unsigned short)p;
        sL[row * STR + c1] = (unsigned short)(p >> 16);
      }
    }
    __syncthreads();
  }

  // ---- merge2: l3 = A·( l2@Wm2top + A·(w1@Wm2bot) ) + bm2  -> f32 LDS ----
  {
    float4v acc0[9], acc1[9];
    #pragma unroll
    for (int m = 0; m < 9; ++m) {
      float4v z = {0.f,0.f,0.f,0.f};
      acc0[m] = z; acc1[m] = z;
    }
    #pragma unroll
    for (int kk = 0; kk < 8; ++kk) {      // w-half: w1 @ Wm2bot (K 256..511)
      short8 b0 = *(const short8*)(Wm2t + c0 * 512 + (kk + 8) * 32 + g4 * 8);
      short8 b1 = *(const short8*)(Wm2t + c1 * 512 + (kk + 8) * 32 + g4 * 8);
      #pragma unroll
      for (int m = 0; m < 9; ++m) {
        short8 a = *(const short8*)(sW + (m * 16 + lane16) * STR + kk * 32 + g4 * 8);
        acc0[m] = mfma16(a, b0, acc0[m]);
        acc1[m] = mfma16(a, b1, acc1[m]);
      }
    }
    applyA(acc0); applyA(acc1);           // inner A (w-path), pure registers
    #pragma unroll
    for (int kk = 0; kk < 8; ++kk) {      // l-half: l2 @ Wm2top, accumulate on top
      short8 b0 = *(const short8*)(Wm2t + c0 * 512 + kk * 32 + g4 * 8);
      short8 b1 = *(const short8*)(Wm2t + c1 * 512 + kk * 32 + g4 * 8);
      #pragma unroll
      for (int m = 0; m < 9; ++m) {
        short8 a = *(const short8*)(sL + (m * 16 + lane16) * STR + kk * 32 + g4 * 8);
        acc0[m] = mfma16(a, b0, acc0[m]);
        acc1[m] = mfma16(a, b1, acc1[m]);
      }
    }
    __syncthreads();   // all sL/sW reads complete before f32 overwrite of sBuf
    applyA(acc0); applyA(acc1);           // outer A
    float bia0 = bm2[c0], bia1 = bm2[c1];
    float* f3 = (float*)sBuf;
    #pragma unroll
    for (int m = 0; m < 9; ++m) {
      #pragma unroll
      for (int i = 0; i < 4; ++i) {
        int row = m * 16 + g4 * 4 + i;
        f3[row * F32STR + c0] = acc0[m][i] + bia0;
        f3[row * F32STR + c1] = acc1[m][i] + bia1;
      }
    }
    __syncthreads();
  }

  // ---- final regression: out[b] = sum_{d,h} l3[d*16+s][h] * Wreg[d*256+h] + breg ----
  {
    int s = tid >> 5;
    int t32 = tid & 31;
    int h0 = t32 << 3;
    const float* f3 = (const float*)sBuf;
    float sum = 0.f;
    #pragma unroll
    for (int d = 0; d < 9; ++d) {
      const float* rp = f3 + (d * 16 + s) * F32STR + h0;
      float4v x0 = *(const float4v*)(rp);
      float4v x1 = *(const float4v*)(rp + 4);
      float4v r0 = *(const float4v*)(Wreg + d * 256 + h0);
      float4v r1 = *(const float4v*)(Wreg + d * 256 + h0 + 4);
      #pragma unroll
      for (int e = 0; e < 4; ++e) sum = fmaf(x0[e], r0[e], sum);
      #pragma unroll
      for (int e = 0; e < 4; ++e) sum = fmaf(x1[e], r1[e], sum);
    }
    sum += __shfl_down(sum, 16, 32);
    sum += __shfl_down(sum, 8, 32);
    sum += __shfl_down(sum, 4, 32);
    sum += __shfl_down(sum, 2, 32);
    sum += __shfl_down(sum, 1, 32);
    if (t32 == 0) out[s0 + s] = sum + breg[0];
  }
}

extern "C" void kernel_launch(void* const* d_in, const int* in_sizes, int n_in,
                              void* d_out, int out_size, void* d_ws, size_t ws_size,
                              hipStream_t stream) {
  const float* lags    = (const float*)d_in[0];
  const float* weather = (const float*)d_in[1];
  const float* Wl1     = (const float*)d_in[2];
  const float* bl1     = (const float*)d_in[3];
  const float* gbn     = (const float*)d_in[4];
  const float* bbn     = (const float*)d_in[5];
  const float* Wl2     = (const float*)d_in[6];
  const float* bl2     = (const float*)d_in[7];
  const float* Ww1     = (const float*)d_in[8];
  const float* bw1     = (const float*)d_in[9];
  const float* Ww2     = (const float*)d_in[10];
  const float* bw2     = (const float*)d_in[11];
  const float* Wm1     = (const float*)d_in[12];
  const float* bm1     = (const float*)d_in[13];
  const float* Wm2     = (const float*)d_in[14];
  const float* bm2     = (const float*)d_in[15];
  const float* Wreg    = (const float*)d_in[16];
  const float* breg    = (const float*)d_in[17];
  unsigned short* ws = (unsigned short*)d_ws;

  prep_kernel<<<1568, 256, 0, stream>>>(Wl2, Ww2, Wm1, Wm2, Ww1, ws);

  const int nblocks = 32768 / GSAMP;  // 2048
  fused_kernel<<<nblocks, NTHREADS, 0, stream>>>(
      lags, weather, Wl1, bl1, gbn, bbn, bl2, bw1, bw2, bm1, bm2,
      Wreg, breg, ws, (float*)d_out);
}

// Round 11
// 418.708 us; speedup vs baseline: 1.5573x; 1.0008x over previous
//
#include <hip/hip_runtime.h>

typedef __attribute__((ext_vector_type(8))) short short8;
typedef __attribute__((ext_vector_type(4))) float float4v;

#define NLAGS 9
#define HID 256
#define GSAMP 16
#define MROWS 144          // 9 lag-tiles of 16 samples (LAG-MAJOR: row = lag*16 + sample)
#define STR 264            // LDS row stride in bf16 elems
#define F32STR 260         // f32 row stride for final l3 buffer
#define NTHREADS 512
#define SBUF_SHORTS (2 * MROWS * STR)   // 152,064 B (1 block/CU)

union S8 { short8 v; unsigned short u[8]; };

__device__ __forceinline__ float b2f(unsigned short u) {
  union { unsigned int i; float f; } c; c.i = ((unsigned int)u) << 16; return c.f;
}
__device__ __forceinline__ unsigned short f2b(float f) {
  union { float f; unsigned int i; } c; c.f = f;
  return (unsigned short)((c.i + 0x7FFFu + ((c.i >> 16) & 1u)) >> 16);  // RNE
}
__device__ __forceinline__ float sane(float x) {
  return (__builtin_isfinite(x) && fabsf(x) < 1e30f) ? x : 0.0f;
}
// HW packed f32->bf16 (RNE), 1 VALU op for 2 conversions
__device__ __forceinline__ unsigned int pkbf16(float lo, float hi) {
  unsigned int r;
  asm("v_cvt_pk_bf16_f32 %0, %1, %2" : "=v"(r) : "v"(lo), "v"(hi));
  return r;
}
// unclamped tanh: exp->0 gives -1, exp->inf gives +1; finite-in => finite-out
// NOTE r8-r10: every variant of (bias-init-in-C, exp2-tanh, XOR-swizzle) on top of
// this kernel FAILED correctness with scheduling-dependent absmax. Do not re-add
// without isolating. This file is the verbatim round-7 PASSING kernel (378us).
__device__ __forceinline__ float ftanh(float x) {
  float t = __expf(2.0f * x);
  return 1.0f - 2.0f * __builtin_amdgcn_rcpf(t + 1.0f);
}
__device__ __forceinline__ float4v mfma16(short8 a, short8 b, float4v c) {
  return __builtin_amdgcn_mfma_f32_16x16x32_bf16(a, b, c, 0, 0, 0);
}

// ---- prep: f32 weights -> transposed bf16 copies in ws (sanitized once here) ----
// layout (bf16 elems): Wl2t[256][256] @0, Ww2t @65536, Wm1t[256][512] @131072,
//                      Wm2t[256][512] @262144, Ww1p[256][32] @393216 (K padded 8->32)
__global__ void prep_kernel(const float* __restrict__ Wl2,
                            const float* __restrict__ Ww2,
                            const float* __restrict__ Wm1,
                            const float* __restrict__ Wm2,
                            const float* __restrict__ Ww1,
                            unsigned short* __restrict__ ws)
{
  int idx = blockIdx.x * 256 + threadIdx.x;   // 0..401407
  if (idx < 65536) {
    int n = idx >> 8, k = idx & 255;
    ws[idx] = f2b(sane(Wl2[k * 256 + n]));
  } else if (idx < 131072) {
    int j = idx - 65536; int n = j >> 8, k = j & 255;
    ws[idx] = f2b(sane(Ww2[k * 256 + n]));
  } else if (idx < 262144) {
    int j = idx - 131072; int n = j >> 9, k = j & 511;
    ws[idx] = f2b(sane(Wm1[k * 256 + n]));
  } else if (idx < 393216) {
    int j = idx - 262144; int n = j >> 9, k = j & 511;
    ws[idx] = f2b(sane(Wm2[k * 256 + n]));
  } else if (idx < 401408) {
    int j = idx - 393216; int n = j >> 5, k = j & 31;
    ws[idx] = (k < 8) ? f2b(sane(Ww1[k * 256 + n])) : (unsigned short)0;
  }
}

__global__ void __launch_bounds__(NTHREADS, 2)
fused_kernel(const float* __restrict__ lags,
             const float* __restrict__ weather,
             const float* __restrict__ Wl1,
             const float* __restrict__ bl1,
             const float* __restrict__ gbn,
             const float* __restrict__ bbn,
             const float* __restrict__ bl2,
             const float* __restrict__ bw1,
             const float* __restrict__ bw2,
             const float* __restrict__ bm1,
             const float* __restrict__ bm2,
             const float* __restrict__ Wreg,
             const float* __restrict__ breg,
             const unsigned short* __restrict__ ws,
             float* __restrict__ out)
{
  __shared__ __align__(16) unsigned short sBuf[SBUF_SHORTS];  // 152,064 B
  unsigned short* sL = sBuf;
  unsigned short* sW = sBuf + MROWS * STR;

  const int tid = threadIdx.x;
  const int wave = tid >> 6;
  const int lane16 = tid & 15;
  const int g4 = (tid >> 4) & 3;
  const int s0 = blockIdx.x * GSAMP;

  const unsigned short* Wl2t = ws;
  const unsigned short* Ww2t = ws + 65536;
  const unsigned short* Wm1t = ws + 131072;
  const unsigned short* Wm2t = ws + 262144;
  const unsigned short* Ww1p = ws + 393216;

  const int c0 = wave * 32 + lane16;       // wave's two output columns
  const int c1 = wave * 32 + 16 + lane16;

  // in-register lag-axis aggregation: acc[m] indexed by lag tile m
  auto applyA = [&](float4v (&a)[9]) {
    #pragma unroll
    for (int i = 0; i < 4; ++i) {
      float v0=a[0][i],v1=a[1][i],v2=a[2][i],v3=a[3][i],v4=a[4][i];
      float v5=a[5][i],v6=a[6][i],v7=a[7][i],v8=a[8][i];
      a[0][i]=v8;
      a[1][i]=v0;
      a[2][i]=(1.f/3.f)*v0+(2.f/3.f)*v1;
      a[3][i]=0.2f*v0+0.4f*v1+0.4f*v2;
      a[4][i]=0.2f*v1+0.4f*v2+0.4f*v3;
      a[5][i]=0.2f*v2+0.4f*v3+0.4f*v4;
      a[6][i]=0.2f*v3+0.4f*v4+0.4f*v5;
      a[7][i]=0.25f*v4+0.5f*v5+0.25f*v6;
      a[8][i]=(1.f/3.f)*(v5+v6+v7);
    }
  };

  // ---- Phase A: l0 = BN(tanh(lag*Wl1+bl1)) -> sL, lag-major rows ----
  {
    const float BNS = 0.99999500003750f;  // 1/sqrt(1+1e-5)
    const int samp = tid >> 5;            // 0..15
    const int h0 = (tid & 31) << 3;       // fixed col chunk per thread
    float4v w0 = *(const float4v*)(Wl1 + h0);
    float4v w1 = *(const float4v*)(Wl1 + h0 + 4);
    float4v a0 = *(const float4v*)(bl1 + h0);
    float4v a1 = *(const float4v*)(bl1 + h0 + 4);
    float4v g0 = *(const float4v*)(gbn + h0);
    float4v g1 = *(const float4v*)(gbn + h0 + 4);
    float4v q0 = *(const float4v*)(bbn + h0);
    float4v q1 = *(const float4v*)(bbn + h0 + 4);
    #pragma unroll
    for (int e = 0; e < 4; ++e) { g0[e] *= BNS; g1[e] *= BNS; }
    #pragma unroll
    for (int d = 0; d < 9; ++d) {         // d = lag
      int row = d * 16 + samp;
      float lag = lags[(s0 + samp) * NLAGS + d];
      float t[8];
      #pragma unroll
      for (int e = 0; e < 4; ++e) {
        float v = ftanh(fmaf(lag, w0[e], a0[e]));
        t[e] = fmaf(v, g0[e], q0[e]);
        float v2 = ftanh(fmaf(lag, w1[e], a1[e]));
        t[e + 4] = fmaf(v2, g1[e], q1[e]);
      }
      uint4 o;
      o.x = pkbf16(t[0], t[1]); o.y = pkbf16(t[2], t[3]);
      o.z = pkbf16(t[4], t[5]); o.w = pkbf16(t[6], t[7]);
      *(uint4*)(sL + row * STR + h0) = o;
    }
  }

  // ---- Phase B: w0 = tanh(weather @ Ww1 + bw1) -> sW (K pad 8->32) ----
  {
    float4v acc0[9], acc1[9];
    short8 bf0 = *(const short8*)(Ww1p + c0 * 32 + g4 * 8);
    short8 bf1 = *(const short8*)(Ww1p + c1 * 32 + g4 * 8);
    #pragma unroll
    for (int m = 0; m < 9; ++m) {         // m = lag tile; row-in-tile = sample = lane16
      S8 a8;
      if (g4 == 0) {
        const float* wp = weather + (size_t)(s0 + lane16) * 72 + m * 8;
        float4v x0 = *(const float4v*)(wp);
        float4v x1 = *(const float4v*)(wp + 4);
        a8.v = (short8){0,0,0,0,0,0,0,0};
        unsigned int p0 = pkbf16(x0[0], x0[1]), p1 = pkbf16(x0[2], x0[3]);
        unsigned int p2 = pkbf16(x1[0], x1[1]), p3 = pkbf16(x1[2], x1[3]);
        a8.u[0] = (unsigned short)p0; a8.u[1] = (unsigned short)(p0 >> 16);
        a8.u[2] = (unsigned short)p1; a8.u[3] = (unsigned short)(p1 >> 16);
        a8.u[4] = (unsigned short)p2; a8.u[5] = (unsigned short)(p2 >> 16);
        a8.u[6] = (unsigned short)p3; a8.u[7] = (unsigned short)(p3 >> 16);
      } else {
        a8.v = (short8){0,0,0,0,0,0,0,0};
      }
      float4v zz = {0.f, 0.f, 0.f, 0.f};
      acc0[m] = mfma16(a8.v, bf0, zz);
      acc1[m] = mfma16(a8.v, bf1, zz);
    }
    float bia0 = bw1[c0], bia1 = bw1[c1];
    #pragma unroll
    for (int m = 0; m < 9; ++m) {
      #pragma unroll
      for (int i = 0; i < 4; ++i) {
        int row = m * 16 + g4 * 4 + i;    // C/D: col=lane&15, row=(lane>>4)*4+i
        unsigned int p = pkbf16(ftanh(acc0[m][i] + bia0), ftanh(acc1[m][i] + bia1));
        sW[row * STR + c0] = (unsigned short)p;
        sW[row * STR + c1] = (unsigned short)(p >> 16);
      }
    }
  }
  __syncthreads();

  // ---- in-place GEMM (K=256): X = tanh(X @ W + b) ----
  auto gemm256 = [&](unsigned short* Abuf, const unsigned short* Bt, const float* bias) {
    float4v acc0[9], acc1[9];
    #pragma unroll
    for (int m = 0; m < 9; ++m) {
      float4v z = {0.f,0.f,0.f,0.f};
      acc0[m] = z; acc1[m] = z;
    }
    #pragma unroll
    for (int kk = 0; kk < 8; ++kk) {
      short8 b0 = *(const short8*)(Bt + c0 * 256 + kk * 32 + g4 * 8);
      short8 b1 = *(const short8*)(Bt + c1 * 256 + kk * 32 + g4 * 8);
      #pragma unroll
      for (int m = 0; m < 9; ++m) {
        short8 a = *(const short8*)(Abuf + (m * 16 + lane16) * STR + kk * 32 + g4 * 8);
        acc0[m] = mfma16(a, b0, acc0[m]);
        acc1[m] = mfma16(a, b1, acc1[m]);
      }
    }
    __syncthreads();   // all waves' A reads complete before in-place overwrite
    float bia0 = bias[c0], bia1 = bias[c1];
    #pragma unroll
    for (int m = 0; m < 9; ++m) {
      #pragma unroll
      for (int i = 0; i < 4; ++i) {
        int row = m * 16 + g4 * 4 + i;
        unsigned int p = pkbf16(ftanh(acc0[m][i] + bia0), ftanh(acc1[m][i] + bia1));
        Abuf[row * STR + c0] = (unsigned short)p;
        Abuf[row * STR + c1] = (unsigned short)(p >> 16);
      }
    }
    __syncthreads();
  };

  gemm256(sL, Wl2t, bl2);   // l1 (lag-major)
  gemm256(sW, Ww2t, bw2);   // w1 -- sW is FINAL after this; never rewritten

  // ---- merge1: l2 = A·(l1@Wm1top + w1@Wm1bot) + bm1  -> sL ----
  {
    float4v acc0[9], acc1[9];
    #pragma unroll
    for (int m = 0; m < 9; ++m) {
      float4v z = {0.f,0.f,0.f,0.f};
      acc0[m] = z; acc1[m] = z;
    }
    #pragma unroll
    for (int kk = 0; kk < 16; ++kk) {
      const unsigned short* Ab = (kk < 8) ? sL : sW;
      int ko = (kk & 7) * 32;
      short8 b0 = *(const short8*)(Wm1t + c0 * 512 + kk * 32 + g4 * 8);
      short8 b1 = *(const short8*)(Wm1t + c1 * 512 + kk * 32 + g4 * 8);
      #pragma unroll
      for (int m = 0; m < 9; ++m) {
        short8 a = *(const short8*)(Ab + (m * 16 + lane16) * STR + ko + g4 * 8);
        acc0[m] = mfma16(a, b0, acc0[m]);
        acc1[m] = mfma16(a, b1, acc1[m]);
      }
    }
    __syncthreads();   // all sL reads complete before overwrite
    applyA(acc0); applyA(acc1);
    float bia0 = bm1[c0], bia1 = bm1[c1];
    #pragma unroll
    for (int m = 0; m < 9; ++m) {
      #pragma unroll
      for (int i = 0; i < 4; ++i) {
        int row = m * 16 + g4 * 4 + i;
        unsigned int p = pkbf16(acc0[m][i] + bia0, acc1[m][i] + bia1);
        sL[row * STR + c0] = (unsigned short)p;
        sL[row * STR + c1] = (unsigned short)(p >> 16);
      }
    }
    __syncthreads();
  }

  // ---- merge2: l3 = A·( l2@Wm2top + A·(w1@Wm2bot) ) + bm2  -> f32 LDS ----
  {
    float4v acc0[9], acc1[9];
    #pragma unroll
    for (int m = 0; m < 9; ++m) {
      float4v z = {0.f,0.f,0.f,0.f};
      acc0[m] = z; acc1[m] = z;
    }
    #pragma unroll
    for (int kk = 0; kk < 8; ++kk) {      // w-half: w1 @ Wm2bot (K 256..511)
      short8 b0 = *(const short8*)(Wm2t + c0 * 512 + (kk + 8) * 32 + g4 * 8);
      short8 b1 = *(const short8*)(Wm2t + c1 * 512 + (kk + 8) * 32 + g4 * 8);
      #pragma unroll
      for (int m = 0; m < 9; ++m) {
        short8 a = *(const short8*)(sW + (m * 16 + lane16) * STR + kk * 32 + g4 * 8);
        acc0[m] = mfma16(a, b0, acc0[m]);
        acc1[m] = mfma16(a, b1, acc1[m]);
      }
    }
    applyA(acc0); applyA(acc1);           // inner A (w-path), pure registers
    #pragma unroll
    for (int kk = 0; kk < 8; ++kk) {      // l-half: l2 @ Wm2top, accumulate on top
      short8 b0 = *(const short8*)(Wm2t + c0 * 512 + kk * 32 + g4 * 8);
      short8 b1 = *(const short8*)(Wm2t + c1 * 512 + kk * 32 + g4 * 8);
      #pragma unroll
      for (int m = 0; m < 9; ++m) {
        short8 a = *(const short8*)(sL + (m * 16 + lane16) * STR + kk * 32 + g4 * 8);
        acc0[m] = mfma16(a, b0, acc0[m]);
        acc1[m] = mfma16(a, b1, acc1[m]);
      }
    }
    __syncthreads();   // all sL/sW reads complete before f32 overwrite of sBuf
    applyA(acc0); applyA(acc1);           // outer A
    float bia0 = bm2[c0], bia1 = bm2[c1];
    float* f3 = (float*)sBuf;
    #pragma unroll
    for (int m = 0; m < 9; ++m) {
      #pragma unroll
      for (int i = 0; i < 4; ++i) {
        int row = m * 16 + g4 * 4 + i;
        f3[row * F32STR + c0] = acc0[m][i] + bia0;
        f3[row * F32STR + c1] = acc1[m][i] + bia1;
      }
    }
    __syncthreads();
  }

  // ---- final regression: out[b] = sum_{d,h} l3[d*16+s][h] * Wreg[d*256+h] + breg ----
  {
    int s = tid >> 5;
    int t32 = tid & 31;
    int h0 = t32 << 3;
    const float* f3 = (const float*)sBuf;
    float sum = 0.f;
    #pragma unroll
    for (int d = 0; d < 9; ++d) {
      const float* rp = f3 + (d * 16 + s) * F32STR + h0;
      float4v x0 = *(const float4v*)(rp);
      float4v x1 = *(const float4v*)(rp + 4);
      float4v r0 = *(const float4v*)(Wreg + d * 256 + h0);
      float4v r1 = *(const float4v*)(Wreg + d * 256 + h0 + 4);
      #pragma unroll
      for (int e = 0; e < 4; ++e) sum = fmaf(x0[e], r0[e], sum);
      #pragma unroll
      for (int e = 0; e < 4; ++e) sum = fmaf(x1[e], r1[e], sum);
    }
    sum += __shfl_down(sum, 16, 32);
    sum += __shfl_down(sum, 8, 32);
    sum += __shfl_down(sum, 4, 32);
    sum += __shfl_down(sum, 2, 32);
    sum += __shfl_down(sum, 1, 32);
    if (t32 == 0) out[s0 + s] = sum + breg[0];
  }
}

extern "C" void kernel_launch(void* const* d_in, const int* in_sizes, int n_in,
                              void* d_out, int out_size, void* d_ws, size_t ws_size,
                              hipStream_t stream) {
  const float* lags    = (const float*)d_in[0];
  const float* weather = (const float*)d_in[1];
  const float* Wl1     = (const float*)d_in[2];
  const float* bl1     = (const float*)d_in[3];
  const float* gbn     = (const float*)d_in[4];
  const float* bbn     = (const float*)d_in[5];
  const float* Wl2     = (const float*)d_in[6];
  const float* bl2     = (const float*)d_in[7];
  const float* Ww1     = (const float*)d_in[8];
  const float* bw1     = (const float*)d_in[9];
  const float* Ww2     = (const float*)d_in[10];
  const float* bw2     = (const float*)d_in[11];
  const float* Wm1     = (const float*)d_in[12];
  const float* bm1     = (const float*)d_in[13];
  const float* Wm2     = (const float*)d_in[14];
  const float* bm2     = (const float*)d_in[15];
  const float* Wreg    = (const float*)d_in[16];
  const float* breg    = (const float*)d_in[17];
  unsigned short* ws = (unsigned short*)d_ws;

  prep_kernel<<<1568, 256, 0, stream>>>(Wl2, Ww2, Wm1, Wm2, Ww1, ws);

  const int nblocks = 32768 / GSAMP;  // 2048
  fused_kernel<<<nblocks, NTHREADS, 0, stream>>>(
      lags, weather, Wl1, bl1, gbn, bbn, bl2, bw1, bw2, bm1, bm2,
      Wreg, breg, ws, (float*)d_out);
}